// Round 1
// baseline (52.326 us; speedup 1.0000x reference)
//
#include <hip/hip_runtime.h>
#include <stdint.h>

typedef __attribute__((ext_vector_type(8))) short short8;
typedef __attribute__((ext_vector_type(4))) float f32x4;
typedef __attribute__((ext_vector_type(4))) unsigned int u32x4;

#define NE 500000
#define NN 50000
#define NTILES 3125   // NN / 16

__device__ __forceinline__ unsigned short f2bf(float f) {
  unsigned int u = __builtin_bit_cast(unsigned int, f);
  u += 0x7FFFu + ((u >> 16) & 1u);   // round-to-nearest-even
  return (unsigned short)(u >> 16);
}

__device__ __forceinline__ short8 pack8(f32x4 a, f32x4 b) {
  short8 r;
  r[0] = (short)f2bf(a[0]); r[1] = (short)f2bf(a[1]);
  r[2] = (short)f2bf(a[2]); r[3] = (short)f2bf(a[3]);
  r[4] = (short)f2bf(b[0]); r[5] = (short)f2bf(b[1]);
  r[6] = (short)f2bf(b[2]); r[7] = (short)f2bf(b[3]);
  return r;
}

// ---------------------------------------------------------------------------
// Kernel 0: repack weights into bf16 MFMA-fragment order.
// Fragment block f (136 total), lane l: 8 bf16 = W[nb*16 + (l&15)][kf*32 + (l>>4)*8 + j]
// stored linearly at wf[f*512 + l*8].  f: [0,8)=W1, [8,40)=W2, [40,72)=W3, [72,136)=W4.
// ---------------------------------------------------------------------------
__global__ __launch_bounds__(256) void prep_weights(
    const float* __restrict__ W1, const float* __restrict__ W2,
    const float* __restrict__ W3, const float* __restrict__ W4,
    unsigned short* __restrict__ wf) {
  int t = blockIdx.x * 256 + threadIdx.x;
  if (t >= 136 * 64) return;
  int f = t >> 6, l = t & 63;
  const float* W; int K, nb, kf;
  if (f < 8)       { W = W1; K = 32;  kf = 0;            nb = f;      }
  else if (f < 40) { W = W2; K = 128; int i = f - 8;  kf = i >> 3; nb = i & 7;  }
  else if (f < 72) { W = W3; K = 128; int i = f - 40; kf = i >> 3; nb = i & 7;  }
  else             { W = W4; K = 128; int i = f - 72; kf = i >> 4; nb = i & 15; }
  const float* src = W + (nb * 16 + (l & 15)) * K + kf * 32 + (l >> 4) * 8;
  f32x4 x0 = *(const f32x4*)src;
  f32x4 x1 = *(const f32x4*)(src + 4);
  *(short8*)(wf + f * 512 + l * 8) = pack8(x0, x1);
}

// ---------------------------------------------------------------------------
// Kernel 1: per-node fused MLP + message@nf -> R[NN][16]
// 4 waves/block, each wave owns 16 nodes/tile, 2 tiles.
// ---------------------------------------------------------------------------
__global__ __launch_bounds__(256) void mlp_kernel(
    const float* __restrict__ ef, const float* __restrict__ nfeat,
    const float* __restrict__ b1, const float* __restrict__ b2,
    const float* __restrict__ b3, const float* __restrict__ b4,
    const unsigned short* __restrict__ wf, float* __restrict__ Rout) {
  __shared__ __align__(16) unsigned short wlds[69632];     // 136 KB weights (fragment order)
  __shared__ __align__(16) unsigned short hlds[4][2048];   // 4 KB H-tile per wave

  const int t = threadIdx.x;
  // stage all weight fragments: 139264 B = 8704 x 16B, 34 iters of 256 threads
  {
    const u32x4* src = (const u32x4*)wf;
    u32x4* dst = (u32x4*)wlds;
    #pragma unroll 4
    for (int i = 0; i < 34; ++i) dst[t + i * 256] = src[t + i * 256];
  }
  __syncthreads();

  const int lane = t & 63, w = t >> 6;
  const int l15 = lane & 15, lg = lane >> 4;

  float bv1[8], bv2[8], bv3[8];
  #pragma unroll
  for (int nb = 0; nb < 8; ++nb) {
    bv1[nb] = b1[nb * 16 + l15];
    bv2[nb] = b2[nb * 16 + l15];
    bv3[nb] = b3[nb * 16 + l15];
  }
  char* hb = (char*)&hlds[w][0];

  // H tile layout: byte(row,col) = (row*256 + col*2) ^ ((row&7)<<4)   (16 rows x 128 bf16)
  auto store_h = [&](const f32x4* a) {
    #pragma unroll
    for (int nb = 0; nb < 8; ++nb) {
      #pragma unroll
      for (int r = 0; r < 4; ++r) {
        int row = lg * 4 + r;                       // C/D layout: row=(lane>>4)*4+reg
        int byte = (row * 256 + (nb * 16 + l15) * 2) ^ ((row & 7) << 4);
        float v = a[nb][r];
        v = v > 0.f ? v : 0.f;                      // ReLU
        *(unsigned short*)(hb + byte) = f2bf(v);
      }
    }
    asm volatile("s_waitcnt lgkmcnt(0)" ::: "memory");
  };
  auto load_a = [&](short8* af) {
    #pragma unroll
    for (int kf = 0; kf < 4; ++kf) {
      int byte = (l15 * 256 + kf * 64 + lg * 16) ^ ((l15 & 7) << 4);
      af[kf] = *(const short8*)(hb + byte);
    }
  };

  for (int rr = 0; rr < 2; ++rr) {
    const int tl = blockIdx.x * 8 + w * 2 + rr;
    if (tl >= NTILES) break;
    const int node0 = tl * 16;

    // ---- layer 1: X(16x32) @ W1^T -> H1(16x128)
    const float* xp = ef + (node0 + l15) * 32 + lg * 8;
    short8 a1 = pack8(*(const f32x4*)xp, *(const f32x4*)(xp + 4));
    f32x4 acc[8];
    #pragma unroll
    for (int nb = 0; nb < 8; ++nb) {
      f32x4 c = { bv1[nb], bv1[nb], bv1[nb], bv1[nb] };
      short8 bw = *(const short8*)&wlds[nb * 512 + lane * 8];
      acc[nb] = __builtin_amdgcn_mfma_f32_16x16x32_bf16(a1, bw, c, 0, 0, 0);
    }
    short8 af[4];
    store_h(acc); load_a(af);

    // ---- layer 2
    #pragma unroll
    for (int nb = 0; nb < 8; ++nb) {
      f32x4 c = { bv2[nb], bv2[nb], bv2[nb], bv2[nb] };
      #pragma unroll
      for (int kf = 0; kf < 4; ++kf) {
        short8 bw = *(const short8*)&wlds[(8 + kf * 8 + nb) * 512 + lane * 8];
        c = __builtin_amdgcn_mfma_f32_16x16x32_bf16(af[kf], bw, c, 0, 0, 0);
      }
      acc[nb] = c;
    }
    store_h(acc); load_a(af);

    // ---- layer 3
    #pragma unroll
    for (int nb = 0; nb < 8; ++nb) {
      f32x4 c = { bv3[nb], bv3[nb], bv3[nb], bv3[nb] };
      #pragma unroll
      for (int kf = 0; kf < 4; ++kf) {
        short8 bw = *(const short8*)&wlds[(40 + kf * 8 + nb) * 512 + lane * 8];
        c = __builtin_amdgcn_mfma_f32_16x16x32_bf16(af[kf], bw, c, 0, 0, 0);
      }
      acc[nb] = c;
    }
    store_h(acc); load_a(af);

    // ---- layer 4, operand-swapped: D[c, m] = sum_k W4[c,k] * H3[m,k]  (+ b4 via acc init)
    // lane holds H4[m = l15][c = nb*16 + lg*4 + r]
    f32x4 acc4[16];
    #pragma unroll
    for (int nb = 0; nb < 16; ++nb) {
      acc4[nb] = *(const f32x4*)(b4 + nb * 16 + lg * 4);
      #pragma unroll
      for (int kf = 0; kf < 4; ++kf) {
        short8 aw = *(const short8*)&wlds[(72 + kf * 16 + nb) * 512 + lane * 8];
        acc4[nb] = __builtin_amdgcn_mfma_f32_16x16x32_bf16(aw, af[kf], acc4[nb], 0, 0, 0);
      }
    }

    // ---- epilogue: out[m, i] = sum_j H4[m, i*16+j] * nf[m, j]
    // lane's 4 regs of block nb cover j = lg*4..lg*4+3 of i = nb
    f32x4 nfv = *(const f32x4*)(nfeat + (node0 + l15) * 16 + lg * 4);
    float o0 = 0.f, o1 = 0.f, o2 = 0.f, o3 = 0.f;
    #pragma unroll
    for (int nb = 0; nb < 16; ++nb) {
      float p = acc4[nb][0] * nfv[0] + acc4[nb][1] * nfv[1]
              + acc4[nb][2] * nfv[2] + acc4[nb][3] * nfv[3];
      p += __shfl_xor(p, 16, 64);   // combine j-groups
      p += __shfl_xor(p, 32, 64);
      int rs = nb - lg * 4;         // static reg index, runtime predicate (no scratch)
      o0 = (rs == 0) ? p : o0;
      o1 = (rs == 1) ? p : o1;
      o2 = (rs == 2) ? p : o2;
      o3 = (rs == 3) ? p : o3;
    }
    f32x4 o = { o0, o1, o2, o3 };
    *(f32x4*)(Rout + (node0 + l15) * 16 + lg * 4) = o;
  }
}

// ---------------------------------------------------------------------------
// Kernel 2: out[e] = R[edge_index[e,1]] ; 4 threads per edge, 16B per lane
// ---------------------------------------------------------------------------
__global__ __launch_bounds__(256) void scatter_kernel(
    const int* __restrict__ eidx, const float* __restrict__ Rbuf,
    float* __restrict__ out) {
  int tid = blockIdx.x * 256 + threadIdx.x;
  const int total = NE * 4;
  const int stride = gridDim.x * 256;
  for (; tid < total; tid += stride) {
    int e = tid >> 2, p = tid & 3;
    int nb = eidx[2 * e + 1];
    f32x4 v = *(const f32x4*)(Rbuf + nb * 16 + p * 4);
    *(f32x4*)(out + e * 16 + p * 4) = v;
  }
}

extern "C" void kernel_launch(void* const* d_in, const int* in_sizes, int n_in,
                              void* d_out, int out_size, void* d_ws, size_t ws_size,
                              hipStream_t stream) {
  const float* ef = (const float*)d_in[0];
  const float* nf = (const float*)d_in[1];
  const float* W1 = (const float*)d_in[2];
  const float* b1 = (const float*)d_in[3];
  const float* W2 = (const float*)d_in[4];
  const float* b2 = (const float*)d_in[5];
  const float* W3 = (const float*)d_in[6];
  const float* b3 = (const float*)d_in[7];
  const float* W4 = (const float*)d_in[8];
  const float* b4 = (const float*)d_in[9];
  const int* eidx = (const int*)d_in[10];

  unsigned short* wf = (unsigned short*)d_ws;                 // 139264 B bf16 fragments
  float* Rbuf = (float*)((char*)d_ws + 139264);               // NN*16 f32 = 3.2 MB
  float* out = (float*)d_out;

  hipLaunchKernelGGL(prep_weights, dim3(34), dim3(256), 0, stream, W1, W2, W3, W4, wf);
  hipLaunchKernelGGL(mlp_kernel, dim3(391), dim3(256), 0, stream,
                     ef, nf, b1, b2, b3, b4, wf, Rbuf);
  hipLaunchKernelGGL(scatter_kernel, dim3(2048), dim3(256), 0, stream, eidx, Rbuf, out);
}

// Round 2
// 45.244 us; speedup vs baseline: 1.1565x; 1.1565x over previous
//
#include <hip/hip_runtime.h>
#include <stdint.h>

typedef __attribute__((ext_vector_type(8))) short short8;
typedef __attribute__((ext_vector_type(4))) float f32x4;
typedef __attribute__((ext_vector_type(4))) unsigned int u32x4;

#define NE 500000
#define NN 50000
#define NTILES 3125
#define NPAIRS 1563   // ceil(NTILES/2), pair 1562 has a phantom second tile

__device__ __forceinline__ unsigned int f2bf1(float f) {
  unsigned int u = __builtin_bit_cast(unsigned int, f);
  u += 0x7FFFu + ((u >> 16) & 1u);   // round-to-nearest-even
  return u >> 16;
}
__device__ __forceinline__ unsigned int packbf2(float lo, float hi) {
  return f2bf1(lo) | (f2bf1(hi) << 16);
}
__device__ __forceinline__ short8 pack8(f32x4 a, f32x4 b) {
  short8 r;
  r[0] = (short)f2bf1(a[0]); r[1] = (short)f2bf1(a[1]);
  r[2] = (short)f2bf1(a[2]); r[3] = (short)f2bf1(a[3]);
  r[4] = (short)f2bf1(b[0]); r[5] = (short)f2bf1(b[1]);
  r[6] = (short)f2bf1(b[2]); r[7] = (short)f2bf1(b[3]);
  return r;
}

// ---------------------------------------------------------------------------
// Kernel 0: repack weights into bf16 MFMA-fragment order.
// Fragment f, lane l: 8 bf16 = W[nb*16 + (l&15)][kf*32 + (l>>4)*8 + j]
// at wf[f*512 + l*8].  f: [0,8)=W1, [8,40)=W2, [40,72)=W3, [72,136)=W4.
// Works as A-operand (m=l15,k=lg*8+j) or B-operand (n=l15,k=lg*8+j).
// ---------------------------------------------------------------------------
__global__ __launch_bounds__(256) void prep_weights(
    const float* __restrict__ W1, const float* __restrict__ W2,
    const float* __restrict__ W3, const float* __restrict__ W4,
    unsigned short* __restrict__ wf) {
  int t = blockIdx.x * 256 + threadIdx.x;
  if (t >= 136 * 64) return;
  int f = t >> 6, l = t & 63;
  const float* W; int K, nb, kf;
  if (f < 8)       { W = W1; K = 32;  kf = 0;            nb = f;      }
  else if (f < 40) { W = W2; K = 128; int i = f - 8;  kf = i >> 3; nb = i & 7;  }
  else if (f < 72) { W = W3; K = 128; int i = f - 40; kf = i >> 3; nb = i & 7;  }
  else             { W = W4; K = 128; int i = f - 72; kf = i >> 4; nb = i & 15; }
  const float* src = W + (nb * 16 + (l & 15)) * K + kf * 32 + (l >> 4) * 8;
  f32x4 x0 = *(const f32x4*)src;
  f32x4 x1 = *(const f32x4*)(src + 4);
  *(short8*)(wf + f * 512 + l * 8) = pack8(x0, x1);
}

// ---------------------------------------------------------------------------
// Kernel 1: per-node fused MLP + message@nf -> R[NN][16]
// 4 waves/block, each wave processes pairs of 16-node tiles (B=2 batching:
// every weight fragment read once from LDS feeds two MFMAs).
// All layers computed operand-swapped: D = W_frag(A) x H_frag(B), so lane
// holds H_next[node=l15][c = nb*16+lg*4+r]  -> packed b64 H-writes.
// ---------------------------------------------------------------------------
__global__ __launch_bounds__(256, 1) void mlp_kernel(
    const float* __restrict__ ef, const float* __restrict__ nfeat,
    const float* __restrict__ b1, const float* __restrict__ b2,
    const float* __restrict__ b3, const float* __restrict__ b4,
    const unsigned short* __restrict__ wf, float* __restrict__ Rout) {
  __shared__ __align__(16) unsigned short wlds[69632];     // 136 KB weight frags
  __shared__ __align__(16) float blds[640];                // b1|b2|b3|b4
  __shared__ __align__(16) unsigned short hlds[4][2048];   // 4 KB H scratch per wave

  const int t = threadIdx.x;
  // stage weight fragments: 8704 x 16B
  {
    const u32x4* src = (const u32x4*)wf;
    u32x4* dst = (u32x4*)wlds;
    #pragma unroll 8
    for (int i = 0; i < 34; ++i) dst[t + i * 256] = src[t + i * 256];
  }
  if (t < 160) {
    const float* s = t < 32 ? b1 + t * 4
                   : t < 64 ? b2 + (t - 32) * 4
                   : t < 96 ? b3 + (t - 64) * 4
                   :          b4 + (t - 96) * 4;
    ((f32x4*)blds)[t] = *(const f32x4*)s;
  }
  __syncthreads();

  const int lane = t & 63, w = t >> 6;
  const int l15 = lane & 15, lg = lane >> 4;
  char* hb = (char*)&hlds[w][0];
  const int swz = (l15 & 7) << 4;

  // H scratch <-> A/B-frag transition (wave-private, sequential reuse per tile)
  auto transition = [&](const f32x4* a, short8* af) {
    #pragma unroll
    for (int nb = 0; nb < 8; ++nb) {
      float v0 = fmaxf(a[nb][0], 0.f), v1 = fmaxf(a[nb][1], 0.f);
      float v2 = fmaxf(a[nb][2], 0.f), v3 = fmaxf(a[nb][3], 0.f);
      unsigned long long dw = (unsigned long long)packbf2(v0, v1)
                            | ((unsigned long long)packbf2(v2, v3) << 32);
      int byte = (l15 * 256 + (nb * 16 + lg * 4) * 2) ^ swz;
      *(unsigned long long*)(hb + byte) = dw;
    }
    asm volatile("s_waitcnt lgkmcnt(0)" ::: "memory");
    __builtin_amdgcn_sched_barrier(0);
    #pragma unroll
    for (int kf = 0; kf < 4; ++kf) {
      int byte = (l15 * 256 + kf * 64 + lg * 16) ^ swz;
      af[kf] = *(const short8*)(hb + byte);
    }
    asm volatile("s_waitcnt lgkmcnt(0)" ::: "memory");  // loads done before next overwrite
    __builtin_amdgcn_sched_barrier(0);
  };

  for (int pit = 0; pit < 2; ++pit) {
    const int p = blockIdx.x * 4 + w + pit * 784;
    if (p >= NPAIRS) continue;
    const int tA = 2 * p, tB = 2 * p + 1;
    const bool actB = (tB < NTILES);
    const int nA = tA * 16, nB = (actB ? tB : tA) * 16;

    // ---- layer 1: D = W1(A) x X^T(B)
    const float* xa = ef + (nA + l15) * 32 + lg * 8;
    const float* xb = ef + (nB + l15) * 32 + lg * 8;
    short8 a1A = pack8(*(const f32x4*)xa, *(const f32x4*)(xa + 4));
    short8 a1B = pack8(*(const f32x4*)xb, *(const f32x4*)(xb + 4));
    f32x4 accA[8], accB[8];
    #pragma unroll
    for (int nb = 0; nb < 8; ++nb) {
      f32x4 c0 = *(const f32x4*)&blds[nb * 16 + lg * 4];
      short8 wv = *(const short8*)&wlds[nb * 512 + lane * 8];
      accA[nb] = __builtin_amdgcn_mfma_f32_16x16x32_bf16(wv, a1A, c0, 0, 0, 0);
      accB[nb] = __builtin_amdgcn_mfma_f32_16x16x32_bf16(wv, a1B, c0, 0, 0, 0);
    }
    short8 afA[4], afB[4];
    transition(accA, afA);
    transition(accB, afB);

    // ---- layer 2
    #pragma unroll
    for (int nb = 0; nb < 8; ++nb) {
      f32x4 c0 = *(const f32x4*)&blds[128 + nb * 16 + lg * 4];
      f32x4 cA = c0, cB = c0;
      #pragma unroll
      for (int kf = 0; kf < 4; ++kf) {
        short8 wv = *(const short8*)&wlds[(8 + kf * 8 + nb) * 512 + lane * 8];
        cA = __builtin_amdgcn_mfma_f32_16x16x32_bf16(wv, afA[kf], cA, 0, 0, 0);
        cB = __builtin_amdgcn_mfma_f32_16x16x32_bf16(wv, afB[kf], cB, 0, 0, 0);
      }
      accA[nb] = cA; accB[nb] = cB;
    }
    transition(accA, afA);
    transition(accB, afB);

    // ---- layer 3
    #pragma unroll
    for (int nb = 0; nb < 8; ++nb) {
      f32x4 c0 = *(const f32x4*)&blds[256 + nb * 16 + lg * 4];
      f32x4 cA = c0, cB = c0;
      #pragma unroll
      for (int kf = 0; kf < 4; ++kf) {
        short8 wv = *(const short8*)&wlds[(40 + kf * 8 + nb) * 512 + lane * 8];
        cA = __builtin_amdgcn_mfma_f32_16x16x32_bf16(wv, afA[kf], cA, 0, 0, 0);
        cB = __builtin_amdgcn_mfma_f32_16x16x32_bf16(wv, afB[kf], cB, 0, 0, 0);
      }
      accA[nb] = cA; accB[nb] = cB;
    }
    transition(accA, afA);
    transition(accB, afB);

    // ---- layer 4 + einsum epilogue, per output block nb (acc stays transient)
    f32x4 nfvA = *(const f32x4*)(nfeat + (nA + l15) * 16 + lg * 4);
    f32x4 nfvB = *(const f32x4*)(nfeat + (nB + l15) * 16 + lg * 4);
    float oA0 = 0.f, oA1 = 0.f, oA2 = 0.f, oA3 = 0.f;
    float oB0 = 0.f, oB1 = 0.f, oB2 = 0.f, oB3 = 0.f;
    #pragma unroll
    for (int nb = 0; nb < 16; ++nb) {
      f32x4 c0 = *(const f32x4*)&blds[384 + nb * 16 + lg * 4];
      f32x4 dA = c0, dB = c0;
      #pragma unroll
      for (int kf = 0; kf < 4; ++kf) {
        short8 wv = *(const short8*)&wlds[(72 + kf * 16 + nb) * 512 + lane * 8];
        dA = __builtin_amdgcn_mfma_f32_16x16x32_bf16(wv, afA[kf], dA, 0, 0, 0);
        dB = __builtin_amdgcn_mfma_f32_16x16x32_bf16(wv, afB[kf], dB, 0, 0, 0);
      }
      // lane holds H4[m=l15][c=nb*16+lg*4+r]; j = lg*4+r, i = nb
      float pA = dA[0] * nfvA[0] + dA[1] * nfvA[1] + dA[2] * nfvA[2] + dA[3] * nfvA[3];
      float pB = dB[0] * nfvB[0] + dB[1] * nfvB[1] + dB[2] * nfvB[2] + dB[3] * nfvB[3];
      pA += __shfl_xor(pA, 16, 64); pA += __shfl_xor(pA, 32, 64);
      pB += __shfl_xor(pB, 16, 64); pB += __shfl_xor(pB, 32, 64);
      int rs = nb - lg * 4;
      oA0 = (rs == 0) ? pA : oA0; oA1 = (rs == 1) ? pA : oA1;
      oA2 = (rs == 2) ? pA : oA2; oA3 = (rs == 3) ? pA : oA3;
      oB0 = (rs == 0) ? pB : oB0; oB1 = (rs == 1) ? pB : oB1;
      oB2 = (rs == 2) ? pB : oB2; oB3 = (rs == 3) ? pB : oB3;
    }
    f32x4 oA = { oA0, oA1, oA2, oA3 };
    *(f32x4*)(Rout + (nA + l15) * 16 + lg * 4) = oA;
    if (actB) {
      f32x4 oB = { oB0, oB1, oB2, oB3 };
      *(f32x4*)(Rout + (nB + l15) * 16 + lg * 4) = oB;
    }
  }
}

// ---------------------------------------------------------------------------
// Kernel 2: out[e] = R[edge_index[e,1]] ; 4 threads per edge, 16B per lane
// ---------------------------------------------------------------------------
__global__ __launch_bounds__(256) void scatter_kernel(
    const int* __restrict__ eidx, const float* __restrict__ Rbuf,
    float* __restrict__ out) {
  int tid = blockIdx.x * 256 + threadIdx.x;
  const int total = NE * 4;
  const int stride = gridDim.x * 256;
  for (; tid < total; tid += stride) {
    int e = tid >> 2, p = tid & 3;
    int nb = eidx[2 * e + 1];
    f32x4 v = *(const f32x4*)(Rbuf + nb * 16 + p * 4);
    *(f32x4*)(out + e * 16 + p * 4) = v;
  }
}

extern "C" void kernel_launch(void* const* d_in, const int* in_sizes, int n_in,
                              void* d_out, int out_size, void* d_ws, size_t ws_size,
                              hipStream_t stream) {
  const float* ef = (const float*)d_in[0];
  const float* nf = (const float*)d_in[1];
  const float* W1 = (const float*)d_in[2];
  const float* b1 = (const float*)d_in[3];
  const float* W2 = (const float*)d_in[4];
  const float* b2 = (const float*)d_in[5];
  const float* W3 = (const float*)d_in[6];
  const float* b3 = (const float*)d_in[7];
  const float* W4 = (const float*)d_in[8];
  const float* b4 = (const float*)d_in[9];
  const int* eidx = (const int*)d_in[10];

  unsigned short* wf = (unsigned short*)d_ws;                 // 139264 B bf16 fragments
  float* Rbuf = (float*)((char*)d_ws + 139264);               // NN*16 f32 = 3.2 MB
  float* out = (float*)d_out;

  hipLaunchKernelGGL(prep_weights, dim3(34), dim3(256), 0, stream, W1, W2, W3, W4, wf);
  hipLaunchKernelGGL(mlp_kernel, dim3(196), dim3(256), 0, stream,
                     ef, nf, b1, b2, b3, b4, wf, Rbuf);
  hipLaunchKernelGGL(scatter_kernel, dim3(2048), dim3(256), 0, stream, eidx, Rbuf, out);
}

// Round 3
// 37.672 us; speedup vs baseline: 1.3890x; 1.2010x over previous
//
#include <hip/hip_runtime.h>
#include <stdint.h>

typedef __attribute__((ext_vector_type(8))) short short8;
typedef __attribute__((ext_vector_type(4))) float f32x4;
typedef __attribute__((ext_vector_type(4))) unsigned int u32x4;

#define NE 500000
#define NN 50000
#define NTILES 3125
#define NPAIRS 1563   // ceil(NTILES/2); pair 1562 has a phantom second tile

__device__ __forceinline__ unsigned int f2bf1(float f) {
  unsigned int u = __builtin_bit_cast(unsigned int, f);
  u += 0x7FFFu + ((u >> 16) & 1u);   // round-to-nearest-even
  return u >> 16;
}
__device__ __forceinline__ unsigned int packbf2(float lo, float hi) {
  return f2bf1(lo) | (f2bf1(hi) << 16);
}
__device__ __forceinline__ short8 pack8(f32x4 a, f32x4 b) {
  short8 r;
  r[0] = (short)f2bf1(a[0]); r[1] = (short)f2bf1(a[1]);
  r[2] = (short)f2bf1(a[2]); r[3] = (short)f2bf1(a[3]);
  r[4] = (short)f2bf1(b[0]); r[5] = (short)f2bf1(b[1]);
  r[6] = (short)f2bf1(b[2]); r[7] = (short)f2bf1(b[3]);
  return r;
}

// ---------------------------------------------------------------------------
// Kernel 0: repack weights into bf16 MFMA-fragment order.
// Fragment f, lane l: 8 bf16 = W[nb*16 + (l&15)][kf*32 + (l>>4)*8 + j]
// at wf[f*512 + l*8].  f: [0,8)=W1, [8,40)=W2, [40,72)=W3, [72,136)=W4.
// ---------------------------------------------------------------------------
__global__ __launch_bounds__(256) void prep_weights(
    const float* __restrict__ W1, const float* __restrict__ W2,
    const float* __restrict__ W3, const float* __restrict__ W4,
    unsigned short* __restrict__ wf) {
  int t = blockIdx.x * 256 + threadIdx.x;
  if (t >= 136 * 64) return;
  int f = t >> 6, l = t & 63;
  const float* W; int K, nb, kf;
  if (f < 8)       { W = W1; K = 32;  kf = 0;            nb = f;      }
  else if (f < 40) { W = W2; K = 128; int i = f - 8;  kf = i >> 3; nb = i & 7;  }
  else if (f < 72) { W = W3; K = 128; int i = f - 40; kf = i >> 3; nb = i & 7;  }
  else             { W = W4; K = 128; int i = f - 72; kf = i >> 4; nb = i & 15; }
  const float* src = W + (nb * 16 + (l & 15)) * K + kf * 32 + (l >> 4) * 8;
  f32x4 x0 = *(const f32x4*)src;
  f32x4 x1 = *(const f32x4*)(src + 4);
  *(short8*)(wf + f * 512 + l * 8) = pack8(x0, x1);
}

// ---------------------------------------------------------------------------
// Kernel 1: per-node fused MLP + message@nf -> R[NN][16]
// 512 threads = 8 waves/block, ONE tile-pair per wave (B=2 weight amortize).
// W1..W3 fragments in LDS (72 KB); W4 fragments read straight from global
// (L2-resident, coalesced). Per-wave A/B H-scratch (2x4 KB) -> one drain pair
// per layer. 2 waves/SIMD for latency hiding.
// ---------------------------------------------------------------------------
__global__ __launch_bounds__(512, 2) void mlp_kernel(
    const float* __restrict__ ef, const float* __restrict__ nfeat,
    const float* __restrict__ b1, const float* __restrict__ b2,
    const float* __restrict__ b3, const float* __restrict__ b4,
    const unsigned short* __restrict__ wf, float* __restrict__ Rout) {
  __shared__ __align__(16) unsigned short wlds[36864];        // 72 KB: W1..W3 frags
  __shared__ __align__(16) float blds[640];                   // b1|b2|b3|b4
  __shared__ __align__(16) unsigned short hlds[8][2][2048];   // per-wave A/B 4KB scratch

  const int t = threadIdx.x;
  // stage W1..W3 fragments: 4608 x 16B = 9 iters x 512 threads
  {
    const u32x4* src = (const u32x4*)wf;
    u32x4* dst = (u32x4*)wlds;
    #pragma unroll
    for (int i = 0; i < 9; ++i) dst[t + i * 512] = src[t + i * 512];
  }
  if (t < 160) {
    const float* s = t < 32 ? b1 + t * 4
                   : t < 64 ? b2 + (t - 32) * 4
                   : t < 96 ? b3 + (t - 64) * 4
                   :          b4 + (t - 96) * 4;
    ((f32x4*)blds)[t] = *(const f32x4*)s;
  }
  __syncthreads();

  const int lane = t & 63, w = t >> 6;
  const int l15 = lane & 15, lg = lane >> 4;
  char* hbA = (char*)&hlds[w][0][0];
  char* hbB = (char*)&hlds[w][1][0];
  const int swz = (l15 & 7) << 4;

  const int p = blockIdx.x * 8 + w;
  if (p >= NPAIRS) return;
  const int tA = 2 * p, tB = 2 * p + 1;
  const bool actB = (tB < NTILES);
  const int nA = tA * 16, nB = (actB ? tB : tA) * 16;

  // ReLU + pack C-layout accs into H scratch (lane holds H[m=l15][c=nb*16+lg*4+r])
  auto trans_store = [&](const f32x4* a, char* hb) {
    #pragma unroll
    for (int nb = 0; nb < 8; ++nb) {
      float v0 = fmaxf(a[nb][0], 0.f), v1 = fmaxf(a[nb][1], 0.f);
      float v2 = fmaxf(a[nb][2], 0.f), v3 = fmaxf(a[nb][3], 0.f);
      unsigned long long dw = (unsigned long long)packbf2(v0, v1)
                            | ((unsigned long long)packbf2(v2, v3) << 32);
      int byte = (l15 * 256 + (nb * 16 + lg * 4) * 2) ^ swz;
      *(unsigned long long*)(hb + byte) = dw;
    }
  };
  auto trans_load = [&](short8* af, char* hb) {
    #pragma unroll
    for (int kf = 0; kf < 4; ++kf) {
      int byte = (l15 * 256 + kf * 64 + lg * 16) ^ swz;
      af[kf] = *(const short8*)(hb + byte);
    }
  };

  // ---- layer 1: D = W1(A) x X^T(B)
  const float* xa = ef + (nA + l15) * 32 + lg * 8;
  const float* xb = ef + (nB + l15) * 32 + lg * 8;
  short8 a1A = pack8(*(const f32x4*)xa, *(const f32x4*)(xa + 4));
  short8 a1B = pack8(*(const f32x4*)xb, *(const f32x4*)(xb + 4));
  f32x4 accA[8], accB[8];
  #pragma unroll
  for (int nb = 0; nb < 8; ++nb) {
    f32x4 c0 = *(const f32x4*)&blds[nb * 16 + lg * 4];
    short8 wv = *(const short8*)&wlds[nb * 512 + lane * 8];
    accA[nb] = __builtin_amdgcn_mfma_f32_16x16x32_bf16(wv, a1A, c0, 0, 0, 0);
    accB[nb] = __builtin_amdgcn_mfma_f32_16x16x32_bf16(wv, a1B, c0, 0, 0, 0);
  }
  short8 afA[4], afB[4];
  trans_store(accA, hbA); trans_store(accB, hbB);
  asm volatile("s_waitcnt lgkmcnt(0)" ::: "memory");
  __builtin_amdgcn_sched_barrier(0);
  trans_load(afA, hbA); trans_load(afB, hbB);
  asm volatile("s_waitcnt lgkmcnt(0)" ::: "memory");
  __builtin_amdgcn_sched_barrier(0);

  // ---- layers 2 and 3 (weights from LDS)
  #pragma unroll
  for (int L = 0; L < 2; ++L) {
    const int wbase = 8 + L * 32, bbase = 128 + L * 128;
    #pragma unroll
    for (int nb = 0; nb < 8; ++nb) {
      f32x4 c0 = *(const f32x4*)&blds[bbase + nb * 16 + lg * 4];
      f32x4 cA = c0, cB = c0;
      #pragma unroll
      for (int kf = 0; kf < 4; ++kf) {
        short8 wv = *(const short8*)&wlds[(wbase + kf * 8 + nb) * 512 + lane * 8];
        cA = __builtin_amdgcn_mfma_f32_16x16x32_bf16(wv, afA[kf], cA, 0, 0, 0);
        cB = __builtin_amdgcn_mfma_f32_16x16x32_bf16(wv, afB[kf], cB, 0, 0, 0);
      }
      accA[nb] = cA; accB[nb] = cB;
    }
    trans_store(accA, hbA); trans_store(accB, hbB);
    asm volatile("s_waitcnt lgkmcnt(0)" ::: "memory");
    __builtin_amdgcn_sched_barrier(0);
    trans_load(afA, hbA); trans_load(afB, hbB);
    asm volatile("s_waitcnt lgkmcnt(0)" ::: "memory");
    __builtin_amdgcn_sched_barrier(0);
  }

  // ---- layer 4 (weights from global/L2) + einsum epilogue
  const short8* w4 = (const short8*)(wf + 72 * 512);   // frag f' = kf*16+nb
  f32x4 nfvA = *(const f32x4*)(nfeat + (nA + l15) * 16 + lg * 4);
  f32x4 nfvB = *(const f32x4*)(nfeat + (nB + l15) * 16 + lg * 4);
  float oA0 = 0.f, oA1 = 0.f, oA2 = 0.f, oA3 = 0.f;
  float oB0 = 0.f, oB1 = 0.f, oB2 = 0.f, oB3 = 0.f;
  #pragma unroll
  for (int nb = 0; nb < 16; ++nb) {
    f32x4 c0 = *(const f32x4*)&blds[384 + nb * 16 + lg * 4];
    f32x4 dA = c0, dB = c0;
    #pragma unroll
    for (int kf = 0; kf < 4; ++kf) {
      short8 wv = w4[(kf * 16 + nb) * 64 + lane];
      dA = __builtin_amdgcn_mfma_f32_16x16x32_bf16(wv, afA[kf], dA, 0, 0, 0);
      dB = __builtin_amdgcn_mfma_f32_16x16x32_bf16(wv, afB[kf], dB, 0, 0, 0);
    }
    // lane holds H4[m=l15][c=nb*16+lg*4+r]; j = lg*4+r, i = nb
    float pA = dA[0] * nfvA[0] + dA[1] * nfvA[1] + dA[2] * nfvA[2] + dA[3] * nfvA[3];
    float pB = dB[0] * nfvB[0] + dB[1] * nfvB[1] + dB[2] * nfvB[2] + dB[3] * nfvB[3];
    pA += __shfl_xor(pA, 16, 64); pA += __shfl_xor(pA, 32, 64);
    pB += __shfl_xor(pB, 16, 64); pB += __shfl_xor(pB, 32, 64);
    int rs = nb - lg * 4;
    oA0 = (rs == 0) ? pA : oA0; oA1 = (rs == 1) ? pA : oA1;
    oA2 = (rs == 2) ? pA : oA2; oA3 = (rs == 3) ? pA : oA3;
    oB0 = (rs == 0) ? pB : oB0; oB1 = (rs == 1) ? pB : oB1;
    oB2 = (rs == 2) ? pB : oB2; oB3 = (rs == 3) ? pB : oB3;
  }
  f32x4 oA = { oA0, oA1, oA2, oA3 };
  *(f32x4*)(Rout + (nA + l15) * 16 + lg * 4) = oA;
  if (actB) {
    f32x4 oB = { oB0, oB1, oB2, oB3 };
    *(f32x4*)(Rout + (nB + l15) * 16 + lg * 4) = oB;
  }
}

// ---------------------------------------------------------------------------
// Kernel 2: out[e] = R[edge_index[e,1]] ; 4 threads per edge, 16B per lane
// ---------------------------------------------------------------------------
__global__ __launch_bounds__(256) void scatter_kernel(
    const int* __restrict__ eidx, const float* __restrict__ Rbuf,
    float* __restrict__ out) {
  int tid = blockIdx.x * 256 + threadIdx.x;
  const int total = NE * 4;
  const int stride = gridDim.x * 256;
  for (; tid < total; tid += stride) {
    int e = tid >> 2, p = tid & 3;
    int nb = eidx[2 * e + 1];
    f32x4 v = *(const f32x4*)(Rbuf + nb * 16 + p * 4);
    *(f32x4*)(out + e * 16 + p * 4) = v;
  }
}

extern "C" void kernel_launch(void* const* d_in, const int* in_sizes, int n_in,
                              void* d_out, int out_size, void* d_ws, size_t ws_size,
                              hipStream_t stream) {
  const float* ef = (const float*)d_in[0];
  const float* nf = (const float*)d_in[1];
  const float* W1 = (const float*)d_in[2];
  const float* b1 = (const float*)d_in[3];
  const float* W2 = (const float*)d_in[4];
  const float* b2 = (const float*)d_in[5];
  const float* W3 = (const float*)d_in[6];
  const float* b3 = (const float*)d_in[7];
  const float* W4 = (const float*)d_in[8];
  const float* b4 = (const float*)d_in[9];
  const int* eidx = (const int*)d_in[10];

  unsigned short* wf = (unsigned short*)d_ws;                 // 139264 B bf16 fragments
  float* Rbuf = (float*)((char*)d_ws + 139264);               // NN*16 f32 = 3.2 MB
  float* out = (float*)d_out;

  hipLaunchKernelGGL(prep_weights, dim3(34), dim3(256), 0, stream, W1, W2, W3, W4, wf);
  hipLaunchKernelGGL(mlp_kernel, dim3(196), dim3(512), 0, stream,
                     ef, nf, b1, b2, b3, b4, wf, Rbuf);
  hipLaunchKernelGGL(scatter_kernel, dim3(2048), dim3(256), 0, stream, eidx, Rbuf, out);
}

// Round 4
// 36.279 us; speedup vs baseline: 1.4423x; 1.0384x over previous
//
#include <hip/hip_runtime.h>
#include <stdint.h>

typedef __attribute__((ext_vector_type(8))) short short8;
typedef __attribute__((ext_vector_type(4))) float f32x4;
typedef __attribute__((ext_vector_type(4))) unsigned int u32x4;

#define NE 500000
#define NN 50000
#define NTILES 3125
#define NPAIRS 1563   // ceil(NTILES/2); pair 1562 has a phantom second tile

__device__ __forceinline__ unsigned int f2bf1(float f) {
  unsigned int u = __builtin_bit_cast(unsigned int, f);
  u += 0x7FFFu + ((u >> 16) & 1u);   // round-to-nearest-even
  return u >> 16;
}
__device__ __forceinline__ unsigned int packbf2(float lo, float hi) {
  return f2bf1(lo) | (f2bf1(hi) << 16);
}
__device__ __forceinline__ short8 pack8(f32x4 a, f32x4 b) {
  short8 r;
  r[0] = (short)f2bf1(a[0]); r[1] = (short)f2bf1(a[1]);
  r[2] = (short)f2bf1(a[2]); r[3] = (short)f2bf1(a[3]);
  r[4] = (short)f2bf1(b[0]); r[5] = (short)f2bf1(b[1]);
  r[6] = (short)f2bf1(b[2]); r[7] = (short)f2bf1(b[3]);
  return r;
}

// ---------------------------------------------------------------------------
// Fused MLP kernel. 512 threads = 8 waves, one tile-pair per wave (B=2).
// Staging: every block repacks W1..W4 (raw f32, global) into bf16 MFMA
// fragments in LDS (136 KB) -- fused former prep kernel.
//
// k-relabeling trick: for layers 2..4 (K=128), fragment slot (kf, g, j) maps
// to actual k = (kf + 4*(j>>2))*16 + g*4 + (j&3). Applied to BOTH the weight
// fragments (at pack time) and the H fragments; MFMA is invariant to the
// relabeling. With this labeling the H fragment for the next layer is just a
// register repack of the lane's own C/D output (lane (m,g) holds
// H[m][nb*16+g*4+r]) -> NO cross-lane transition, no LDS scratch, no drains.
// ---------------------------------------------------------------------------
__global__ __launch_bounds__(512, 2) void mlp_kernel(
    const float* __restrict__ ef, const float* __restrict__ nfeat,
    const float* __restrict__ W1, const float* __restrict__ b1,
    const float* __restrict__ W2, const float* __restrict__ b2,
    const float* __restrict__ W3, const float* __restrict__ b3,
    const float* __restrict__ W4, const float* __restrict__ b4,
    float* __restrict__ Rout) {
  __shared__ __align__(16) unsigned short wlds[69632];   // 136 KB: 136 frags x 512 u16
  __shared__ __align__(16) float blds[640];              // b1|b2|b3|b4

  const int t = threadIdx.x;
  // ---- staging: repack weights into fragment order (8704 lane-tasks)
  #pragma unroll
  for (int i = 0; i < 17; ++i) {
    int idx = t + i * 512;
    int f = idx >> 6, l = idx & 63;
    int c2 = l & 15, g = l >> 4;
    const float *pa, *pb;
    if (f < 8) {                       // W1: standard slot layout (K=32)
      const float* base = W1 + (f * 16 + c2) * 32 + g * 8;
      pa = base; pb = base + 4;
    } else {                           // W2/W3/W4: pi-relabeled (K=128)
      const float* W; int i2, kfq, nb;
      if (f < 40)      { W = W2; i2 = f - 8;  kfq = i2 >> 3; nb = i2 & 7;  }
      else if (f < 72) { W = W3; i2 = f - 40; kfq = i2 >> 3; nb = i2 & 7;  }
      else             { W = W4; i2 = f - 72; kfq = i2 >> 4; nb = i2 & 15; }
      const float* base = W + (nb * 16 + c2) * 128 + g * 4;
      pa = base + kfq * 16;            // j=0..3  -> k = kfq*16 + g*4 + j
      pb = base + (kfq + 4) * 16;      // j=4..7  -> k = (kfq+4)*16 + g*4 + (j-4)
    }
    f32x4 x0 = *(const f32x4*)pa;
    f32x4 x1 = *(const f32x4*)pb;
    *(short8*)&wlds[f * 512 + l * 8] = pack8(x0, x1);
  }
  if (t < 160) {
    const float* s = t < 32 ? b1 + t * 4
                   : t < 64 ? b2 + (t - 32) * 4
                   : t < 96 ? b3 + (t - 64) * 4
                   :          b4 + (t - 96) * 4;
    ((f32x4*)blds)[t] = *(const f32x4*)s;
  }
  __syncthreads();

  const int lane = t & 63, w = t >> 6;
  const int l15 = lane & 15, lg = lane >> 4;

  const int p = blockIdx.x * 8 + w;
  if (p >= NPAIRS) return;
  const int tA = 2 * p, tB = 2 * p + 1;
  const bool actB = (tB < NTILES);
  const int nA = tA * 16, nB = (actB ? tB : tA) * 16;

  // ReLU + pack C-layout acc into next-layer A-fragments (pure registers)
  auto transition = [&](const f32x4* a, short8* af) {
    unsigned int pk[8][2];
    #pragma unroll
    for (int nb = 0; nb < 8; ++nb) {
      pk[nb][0] = packbf2(fmaxf(a[nb][0], 0.f), fmaxf(a[nb][1], 0.f));
      pk[nb][1] = packbf2(fmaxf(a[nb][2], 0.f), fmaxf(a[nb][3], 0.f));
    }
    #pragma unroll
    for (int kf = 0; kf < 4; ++kf) {
      u32x4 u = { pk[kf][0], pk[kf][1], pk[kf + 4][0], pk[kf + 4][1] };
      af[kf] = __builtin_bit_cast(short8, u);
    }
  };

  // ---- layer 1: D = W1(A) x X^T(B), standard slots
  const float* xa = ef + (nA + l15) * 32 + lg * 8;
  const float* xb = ef + (nB + l15) * 32 + lg * 8;
  short8 a1A = pack8(*(const f32x4*)xa, *(const f32x4*)(xa + 4));
  short8 a1B = pack8(*(const f32x4*)xb, *(const f32x4*)(xb + 4));
  f32x4 accA[8], accB[8];
  #pragma unroll
  for (int nb = 0; nb < 8; ++nb) {
    f32x4 c0 = *(const f32x4*)&blds[nb * 16 + lg * 4];
    short8 wv = *(const short8*)&wlds[nb * 512 + lane * 8];
    accA[nb] = __builtin_amdgcn_mfma_f32_16x16x32_bf16(wv, a1A, c0, 0, 0, 0);
    accB[nb] = __builtin_amdgcn_mfma_f32_16x16x32_bf16(wv, a1B, c0, 0, 0, 0);
  }
  short8 afA[4], afB[4];
  transition(accA, afA);
  transition(accB, afB);

  // ---- layers 2 and 3 (pi-relabeled weights from LDS)
  #pragma unroll
  for (int L = 0; L < 2; ++L) {
    const int wbase = 8 + L * 32, bbase = 128 + L * 128;
    #pragma unroll
    for (int nb = 0; nb < 8; ++nb) {
      f32x4 c0 = *(const f32x4*)&blds[bbase + nb * 16 + lg * 4];
      f32x4 cA = c0, cB = c0;
      #pragma unroll
      for (int kf = 0; kf < 4; ++kf) {
        short8 wv = *(const short8*)&wlds[(wbase + kf * 8 + nb) * 512 + lane * 8];
        cA = __builtin_amdgcn_mfma_f32_16x16x32_bf16(wv, afA[kf], cA, 0, 0, 0);
        cB = __builtin_amdgcn_mfma_f32_16x16x32_bf16(wv, afB[kf], cB, 0, 0, 0);
      }
      accA[nb] = cA; accB[nb] = cB;
    }
    transition(accA, afA);
    transition(accB, afB);
  }

  // ---- layer 4 (pi-relabeled weights from LDS) + einsum epilogue
  f32x4 nfvA = *(const f32x4*)(nfeat + (nA + l15) * 16 + lg * 4);
  f32x4 nfvB = *(const f32x4*)(nfeat + (nB + l15) * 16 + lg * 4);
  float oA0 = 0.f, oA1 = 0.f, oA2 = 0.f, oA3 = 0.f;
  float oB0 = 0.f, oB1 = 0.f, oB2 = 0.f, oB3 = 0.f;
  #pragma unroll
  for (int nb = 0; nb < 16; ++nb) {
    f32x4 c0 = *(const f32x4*)&blds[384 + nb * 16 + lg * 4];
    f32x4 dA = c0, dB = c0;
    #pragma unroll
    for (int kf = 0; kf < 4; ++kf) {
      short8 wv = *(const short8*)&wlds[(72 + kf * 16 + nb) * 512 + lane * 8];
      dA = __builtin_amdgcn_mfma_f32_16x16x32_bf16(wv, afA[kf], dA, 0, 0, 0);
      dB = __builtin_amdgcn_mfma_f32_16x16x32_bf16(wv, afB[kf], dB, 0, 0, 0);
    }
    // lane holds H4[m=l15][c=nb*16+lg*4+r]; j = lg*4+r, i = nb
    float pA = dA[0] * nfvA[0] + dA[1] * nfvA[1] + dA[2] * nfvA[2] + dA[3] * nfvA[3];
    float pB = dB[0] * nfvB[0] + dB[1] * nfvB[1] + dB[2] * nfvB[2] + dB[3] * nfvB[3];
    pA += __shfl_xor(pA, 16, 64); pA += __shfl_xor(pA, 32, 64);
    pB += __shfl_xor(pB, 16, 64); pB += __shfl_xor(pB, 32, 64);
    int rs = nb - lg * 4;
    oA0 = (rs == 0) ? pA : oA0; oA1 = (rs == 1) ? pA : oA1;
    oA2 = (rs == 2) ? pA : oA2; oA3 = (rs == 3) ? pA : oA3;
    oB0 = (rs == 0) ? pB : oB0; oB1 = (rs == 1) ? pB : oB1;
    oB2 = (rs == 2) ? pB : oB2; oB3 = (rs == 3) ? pB : oB3;
  }
  f32x4 oA = { oA0, oA1, oA2, oA3 };
  *(f32x4*)(Rout + (nA + l15) * 16 + lg * 4) = oA;
  if (actB) {
    f32x4 oB = { oB0, oB1, oB2, oB3 };
    *(f32x4*)(Rout + (nB + l15) * 16 + lg * 4) = oB;
  }
}

// ---------------------------------------------------------------------------
// Scatter: out[e] = R[edge_index[e,1]] ; 4 threads/edge, 16B/lane.
// Nontemporal stores keep the 32 MB output stream from evicting R in L2.
// ---------------------------------------------------------------------------
__global__ __launch_bounds__(256) void scatter_kernel(
    const int* __restrict__ eidx, const float* __restrict__ Rbuf,
    float* __restrict__ out) {
  int tid = blockIdx.x * 256 + threadIdx.x;
  const int total = NE * 4;
  const int stride = gridDim.x * 256;
  for (; tid < total; tid += stride) {
    int e = tid >> 2, p = tid & 3;
    int nb = eidx[2 * e + 1];
    f32x4 v = *(const f32x4*)(Rbuf + nb * 16 + p * 4);
    __builtin_nontemporal_store(v, (f32x4*)(out + e * 16 + p * 4));
  }
}

extern "C" void kernel_launch(void* const* d_in, const int* in_sizes, int n_in,
                              void* d_out, int out_size, void* d_ws, size_t ws_size,
                              hipStream_t stream) {
  const float* ef = (const float*)d_in[0];
  const float* nf = (const float*)d_in[1];
  const float* W1 = (const float*)d_in[2];
  const float* b1 = (const float*)d_in[3];
  const float* W2 = (const float*)d_in[4];
  const float* b2 = (const float*)d_in[5];
  const float* W3 = (const float*)d_in[6];
  const float* b3 = (const float*)d_in[7];
  const float* W4 = (const float*)d_in[8];
  const float* b4 = (const float*)d_in[9];
  const int* eidx = (const int*)d_in[10];

  float* Rbuf = (float*)d_ws;                 // NN*16 f32 = 3.2 MB
  float* out = (float*)d_out;

  hipLaunchKernelGGL(mlp_kernel, dim3(256), dim3(512), 0, stream,
                     ef, nf, W1, b1, W2, b2, W3, b3, W4, b4, Rbuf);
  hipLaunchKernelGGL(scatter_kernel, dim3(2048), dim3(256), 0, stream, eidx, Rbuf, out);
}